// Round 21
// baseline (64.543 us; speedup 1.0000x reference)
//
#include <hip/hip_runtime.h>
#include <hip/hip_bf16.h>
#include <stdint.h>

// CACProjector round 21: r15 structure with 8 waves x 128 cols (one W chunk/wave),
// 2 passes (mi 0..3 / 4..7). Halves per-block LDS x-read traffic (3->1.5 MB),
// keeps 2-pass store spreading. 512 thr, launch_bounds(512,2) for 256-VGPR cap.

#define M_DIM 16384
#define N_DIM 1024
#define K_DIM 768
#define ALPHA_F 10.0f

typedef __bf16 bf16x8 __attribute__((ext_vector_type(8)));
typedef float f32x4 __attribute__((ext_vector_type(4)));

static __device__ __forceinline__ bf16x8 cvt8(f32x4 a, f32x4 b) {
  union { __bf16 h[8]; bf16x8 v; } p;
  p.h[0] = (__bf16)a[0]; p.h[1] = (__bf16)a[1];
  p.h[2] = (__bf16)a[2]; p.h[3] = (__bf16)a[3];
  p.h[4] = (__bf16)b[0]; p.h[5] = (__bf16)b[1];
  p.h[6] = (__bf16)b[2]; p.h[7] = (__bf16)b[3];
  return p.v;
}

// ---------------- W fp32 -> bf16, packed in A-fragment order ----------------
// Slot tid (16B): l15=tid&15, q=(tid>>4)&3, mi=(tid>>6)&7, kt=(tid>>9)%24,
// chunk=(tid>>9)/24. Holds W[chunk*128+mi*16+l15][kt*32+q*8 .. +8].
__global__ __launch_bounds__(256) void cvt_w_kernel(const float* __restrict__ Wm,
                                                    unsigned short* __restrict__ Wq) {
  int tid = blockIdx.x * 256 + threadIdx.x;  // 98304 slots
  int l15 = tid & 15;
  int q = (tid >> 4) & 3;
  int mi = (tid >> 6) & 7;
  int rem = tid >> 9;
  int kt = rem % 24;
  int chunk = rem / 24;
  int col = chunk * 128 + mi * 16 + l15;
  int k = kt * 32 + q * 8;
  const f32x4* p = (const f32x4*)(Wm + (size_t)col * K_DIM + k);
  *(bf16x8*)(Wq + (size_t)tid * 8) = cvt8(p[0], p[1]);
}

// ---------------- fused GEMM + distance ----------------
// 512 thr = 8 waves; wave w owns cols [w*128, +128) = packed chunk w.
// Pass0: mi{0..3} kt0..23 (half1 x staged T14-style); store logits (32MB, drains
// under pass1). Pass1: mi{4..7} kt0..23; store logits. Reduce; dist stores.
__global__ __launch_bounds__(512, 2) void fused_kernel(
    const float* __restrict__ X,            // 16384 x 768 f32
    const unsigned short* __restrict__ Wq,  // packed W bf16
    float* __restrict__ logits,             // 16384 x 1024
    float* __restrict__ dist) {             // 16384 x 1024
  __shared__ __align__(16) unsigned short xt[64 * 768];  // 96 KB
  __shared__ float rs[64][8];                            // 2 KB

  const int t = threadIdx.x;
  const int lane = t & 63;
  const int w = t >> 6;       // 0..7
  const int q = lane >> 4;
  const int l15 = lane & 15;

  // XCD swizzle (256 blocks, 32/XCD chunk, bijective)
  const int bid = blockIdx.x;
  const int tm = (bid & 7) * 32 + (bid >> 3);

  const float* Xb = X + (size_t)tm * 64 * K_DIM;

  // ---- stage x half0 (K cols 0..383, slots c 0..47): 3072 slots ----
#pragma unroll
  for (int r = 0; r < 6; ++r) {
    int id = r * 512 + t;
    int row = id / 48;
    int c = id - row * 48;  // 0..47
    const f32x4* g = (const f32x4*)(Xb + (size_t)row * K_DIM + c * 8);
    f32x4 a = g[0], b = g[1];
    *(bf16x8*)(&xt[row * 768 + (c ^ (row & 7)) * 8]) = cvt8(a, b);
  }
  __syncthreads();

  // ---- T14: ISSUE half1 loads now (use 12 K-steps later) ----
  f32x4 hr[12];
  int hrow[6], hc[6];
#pragma unroll
  for (int j = 0; j < 6; ++j) {
    int id = j * 512 + t;
    hrow[j] = id / 48;
    hc[j] = 48 + (id - hrow[j] * 48);  // 48..95
    const f32x4* g = (const f32x4*)(Xb + (size_t)hrow[j] * K_DIM + hc[j] * 8);
    hr[2 * j] = g[0];
    hr[2 * j + 1] = g[1];
  }

  f32x4 acc[8][4] = {};  // [mi][ni]
  float part[4] = {};
  const unsigned short* wchunk = Wq + ((size_t)(w * 24) * 512 + lane) * 8;
  const float a2 = ALPHA_F * ALPHA_F;
  float* Lb = logits + (size_t)tm * 64 * N_DIM + w * 128 + q * 4;
  float* Db = dist + (size_t)tm * 64 * N_DIM + w * 128 + q * 4;

  auto kstep = [&](int kt, int mi0) {
    bf16x8 bx[4];
#pragma unroll
    for (int ni = 0; ni < 4; ++ni) {
      int row = ni * 16 + l15;
      bx[ni] = *(const bf16x8*)(&xt[row * 768 + ((kt * 4 + q) ^ (row & 7)) * 8]);
    }
    const unsigned short* wp = wchunk + (size_t)kt * 512 * 8;
#pragma unroll
    for (int j = 0; j < 4; ++j) {
      bf16x8 af = *(const bf16x8*)(wp + (mi0 + j) * 512);
#pragma unroll
      for (int ni = 0; ni < 4; ++ni)
        acc[mi0 + j][ni] = __builtin_amdgcn_mfma_f32_16x16x32_bf16(af, bx[ni], acc[mi0 + j][ni], 0, 0, 0);
    }
  };

  auto store_pass = [&](int p) {
#pragma unroll
    for (int ni = 0; ni < 4; ++ni) {
      size_t roff = (size_t)(ni * 16 + l15) * N_DIM;
#pragma unroll
      for (int j = 0; j < 4; ++j) {
        f32x4 lv = acc[p * 4 + j][ni];
        *(f32x4*)(Lb + roff + (p * 4 + j) * 16) = lv;
#pragma unroll
        for (int k = 0; k < 4; ++k) part[ni] += lv[k] * lv[k];
      }
    }
  };

  // ---- pass0a: kt 0..11 on half0 (half1 loads in flight) ----
#pragma unroll 2
  for (int kt = 0; kt < 12; ++kt) kstep(kt, 0);

  // ---- WRITE half1 (loads long since landed), sync, continue ----
#pragma unroll
  for (int j = 0; j < 6; ++j)
    *(bf16x8*)(&xt[hrow[j] * 768 + (hc[j] ^ (hrow[j] & 7)) * 8]) =
        cvt8(hr[2 * j], hr[2 * j + 1]);
  __syncthreads();

  // ---- pass0b: kt 12..23 ----
#pragma unroll 2
  for (int kt = 12; kt < 24; ++kt) kstep(kt, 0);
  store_pass(0);  // logits mi{0..3} drain under pass1
  // ---- pass1: kt 0..23 ----
#pragma unroll 2
  for (int kt = 0; kt < 24; ++kt) kstep(kt, 4);
  store_pass(1);

  // ---- cross-lane + cross-wave sumsq reduce ----
#pragma unroll
  for (int m = 16; m <= 32; m <<= 1)
#pragma unroll
    for (int ni = 0; ni < 4; ++ni) part[ni] += __shfl_xor(part[ni], m, 64);
  if (q == 0) {
#pragma unroll
    for (int ni = 0; ni < 4; ++ni) rs[ni * 16 + l15][w] = part[ni];
  }
  __syncthreads();

  float S[4];
#pragma unroll
  for (int ni = 0; ni < 4; ++ni) {
    const float* rp = &rs[ni * 16 + l15][0];
    f32x4 a = *(const f32x4*)(rp + 0);
    f32x4 b = *(const f32x4*)(rp + 4);
    S[ni] = (a[0] + a[1] + a[2] + a[3]) + (b[0] + b[1] + b[2] + b[3]);
  }

  // ---- dist stores (exposed tail) ----
#pragma unroll
  for (int ni = 0; ni < 4; ++ni) {
    size_t roff = (size_t)(ni * 16 + l15) * N_DIM;
#pragma unroll
    for (int mi = 0; mi < 8; ++mi) {
      f32x4 lv = acc[mi][ni];
      f32x4 d;
#pragma unroll
      for (int j = 0; j < 4; ++j)
        d[j] = sqrtf(fmaxf(S[ni] - 2.0f * ALPHA_F * lv[j] + a2, 0.0f));
      *(f32x4*)(Db + roff + mi * 16) = d;
    }
  }
}

extern "C" void kernel_launch(void* const* d_in, const int* in_sizes, int n_in,
                              void* d_out, int out_size, void* d_ws, size_t ws_size,
                              hipStream_t stream) {
  const float* x = (const float*)d_in[0];  // 16384 x 768
  const float* W = (const float*)d_in[1];  // 1024 x 768
  float* logits = (float*)d_out;
  float* dist = logits + (size_t)M_DIM * N_DIM;

  unsigned short* Wq = (unsigned short*)d_ws;  // 1.5 MB packed

  cvt_w_kernel<<<(N_DIM * K_DIM / 8) / 256, 256, 0, stream>>>(W, Wq);
  fused_kernel<<<M_DIM / 64, 512, 0, stream>>>(x, Wq, logits, dist);
}

// Round 22
// 56.103 us; speedup vs baseline: 1.1504x; 1.1504x over previous
//
#include <hip/hip_runtime.h>
#include <hip/hip_bf16.h>
#include <stdint.h>

// CACProjector FINAL (= rounds 15/18/20, verified best: 56.2-56.5us, absmax 0.25).
// Single fused GEMM+distance kernel: BM=64 x full N=1024, 16 waves, x staged once
// to 96KB XOR-swizzled LDS (f32->bf16 in-kernel, T14 async half1), W pre-packed
// bf16 in MFMA-fragment order (L2-resident coalesced loads), barrier-free K-loop,
// 2-pass mi-split so pass0's logits stores drain under pass1, dist from acc.
// Perturbations tried, all regressed: NT stores+inline stage (r14), sub-tiling
// w/ barrier-after-stores (r16), explicit reg pipelining (r17), 3+1 pass split
// (r19), 8-wave/low-LDS-traffic variant (r21). Robust local optimum.

#define M_DIM 16384
#define N_DIM 1024
#define K_DIM 768
#define ALPHA_F 10.0f

typedef __bf16 bf16x8 __attribute__((ext_vector_type(8)));
typedef float f32x4 __attribute__((ext_vector_type(4)));

static __device__ __forceinline__ bf16x8 cvt8(f32x4 a, f32x4 b) {
  union { __bf16 h[8]; bf16x8 v; } p;
  p.h[0] = (__bf16)a[0]; p.h[1] = (__bf16)a[1];
  p.h[2] = (__bf16)a[2]; p.h[3] = (__bf16)a[3];
  p.h[4] = (__bf16)b[0]; p.h[5] = (__bf16)b[1];
  p.h[6] = (__bf16)b[2]; p.h[7] = (__bf16)b[3];
  return p.v;
}

// ---------------- W fp32 -> bf16, packed in A-fragment order ----------------
// Slot tid (16B): l15=tid&15, q=(tid>>4)&3, mi=(tid>>6)&7, kt=(tid>>9)%24,
// chunk=(tid>>9)/24. Holds W[chunk*128+mi*16+l15][kt*32+q*8 .. +8].
__global__ __launch_bounds__(256) void cvt_w_kernel(const float* __restrict__ Wm,
                                                    unsigned short* __restrict__ Wq) {
  int tid = blockIdx.x * 256 + threadIdx.x;  // 98304 slots
  int l15 = tid & 15;
  int q = (tid >> 4) & 3;
  int mi = (tid >> 6) & 7;
  int rem = tid >> 9;
  int kt = rem % 24;
  int chunk = rem / 24;
  int col = chunk * 128 + mi * 16 + l15;
  int k = kt * 32 + q * 8;
  const f32x4* p = (const f32x4*)(Wm + (size_t)col * K_DIM + k);
  *(bf16x8*)(Wq + (size_t)tid * 8) = cvt8(p[0], p[1]);
}

// ---------------- fused GEMM + distance ----------------
// 1024 thr = 16 waves; wave w owns cols [w*64, +64) (packed chunk w>>1, half w&1).
// Pass0: mi{0,1} kt0..23 (half1 x staged T14-style across kt0..11); store logits.
// Pass1: mi{2,3} kt0..23 (pass0 stores drain under it); store logits.
// Cross-wave sumsq reduce; dist stores.
__global__ __launch_bounds__(1024, 4) void fused_kernel(
    const float* __restrict__ X,            // 16384 x 768 f32
    const unsigned short* __restrict__ Wq,  // packed W bf16
    float* __restrict__ logits,             // 16384 x 1024
    float* __restrict__ dist) {             // 16384 x 1024
  __shared__ __align__(16) unsigned short xt[64 * 768];  // 96 KB
  __shared__ float rs[64][16];                           // 4 KB

  const int t = threadIdx.x;
  const int lane = t & 63;
  const int w = t >> 6;       // 0..15
  const int q = lane >> 4;
  const int l15 = lane & 15;

  // XCD swizzle (256 blocks, 32/XCD chunk, bijective)
  const int bid = blockIdx.x;
  const int tm = (bid & 7) * 32 + (bid >> 3);

  const float* Xb = X + (size_t)tm * 64 * K_DIM;

  // ---- stage x half0 (K cols 0..383, slots c 0..47): 3072 slots ----
#pragma unroll
  for (int r = 0; r < 3; ++r) {
    int id = r * 1024 + t;
    int row = id / 48;
    int c = id - row * 48;  // 0..47
    const f32x4* g = (const f32x4*)(Xb + (size_t)row * K_DIM + c * 8);
    f32x4 a = g[0], b = g[1];
    *(bf16x8*)(&xt[row * 768 + (c ^ (row & 7)) * 8]) = cvt8(a, b);
  }
  __syncthreads();

  // ---- T14: ISSUE half1 loads now (use 12 K-steps later) ----
  f32x4 hr[6];
  int hrow[3], hc[3];
#pragma unroll
  for (int j = 0; j < 3; ++j) {
    int id = j * 1024 + t;
    hrow[j] = id / 48;
    hc[j] = 48 + (id - hrow[j] * 48);  // 48..95
    const f32x4* g = (const f32x4*)(Xb + (size_t)hrow[j] * K_DIM + hc[j] * 8);
    hr[2 * j] = g[0];
    hr[2 * j + 1] = g[1];
  }

  f32x4 acc[4][4] = {};  // [mi][ni]
  float part[4] = {};
  const unsigned short* wchunk =
      Wq + ((size_t)((w >> 1) * 24) * 512 + (w & 1) * 256 + lane) * 8;
  const float a2 = ALPHA_F * ALPHA_F;
  float* Lb = logits + (size_t)tm * 64 * N_DIM + w * 64 + q * 4;
  float* Db = dist + (size_t)tm * 64 * N_DIM + w * 64 + q * 4;

  auto kstep = [&](int kt, int mi0) {
    bf16x8 bx[4];
#pragma unroll
    for (int ni = 0; ni < 4; ++ni) {
      int row = ni * 16 + l15;
      bx[ni] = *(const bf16x8*)(&xt[row * 768 + ((kt * 4 + q) ^ (row & 7)) * 8]);
    }
    const unsigned short* wp = wchunk + (size_t)kt * 512 * 8;
    bf16x8 af0 = *(const bf16x8*)(wp + mi0 * 512);
    bf16x8 af1 = *(const bf16x8*)(wp + (mi0 + 1) * 512);
#pragma unroll
    for (int ni = 0; ni < 4; ++ni)
      acc[mi0][ni] = __builtin_amdgcn_mfma_f32_16x16x32_bf16(af0, bx[ni], acc[mi0][ni], 0, 0, 0);
#pragma unroll
    for (int ni = 0; ni < 4; ++ni)
      acc[mi0 + 1][ni] = __builtin_amdgcn_mfma_f32_16x16x32_bf16(af1, bx[ni], acc[mi0 + 1][ni], 0, 0, 0);
  };

  auto store_pass = [&](int p) {
#pragma unroll
    for (int ni = 0; ni < 4; ++ni) {
      size_t roff = (size_t)(ni * 16 + l15) * N_DIM;
#pragma unroll
      for (int j = 0; j < 2; ++j) {
        f32x4 lv = acc[p * 2 + j][ni];
        *(f32x4*)(Lb + roff + (p * 2 + j) * 16) = lv;
#pragma unroll
        for (int k = 0; k < 4; ++k) part[ni] += lv[k] * lv[k];
      }
    }
  };

  // ---- pass0a: kt 0..11 on half0 (half1 loads in flight) ----
#pragma unroll 2
  for (int kt = 0; kt < 12; ++kt) kstep(kt, 0);

  // ---- WRITE half1 (loads long since landed), sync, continue ----
#pragma unroll
  for (int j = 0; j < 3; ++j)
    *(bf16x8*)(&xt[hrow[j] * 768 + (hc[j] ^ (hrow[j] & 7)) * 8]) =
        cvt8(hr[2 * j], hr[2 * j + 1]);
  __syncthreads();

  // ---- pass0b: kt 12..23 ----
#pragma unroll 2
  for (int kt = 12; kt < 24; ++kt) kstep(kt, 0);
  store_pass(0);  // logits mi{0,1} drain under pass1
  // ---- pass1: kt 0..23 ----
#pragma unroll 2
  for (int kt = 0; kt < 24; ++kt) kstep(kt, 2);
  store_pass(1);

  // ---- cross-lane + cross-wave sumsq reduce ----
#pragma unroll
  for (int m = 16; m <= 32; m <<= 1)
#pragma unroll
    for (int ni = 0; ni < 4; ++ni) part[ni] += __shfl_xor(part[ni], m, 64);
  if (q == 0) {
#pragma unroll
    for (int ni = 0; ni < 4; ++ni) rs[ni * 16 + l15][w] = part[ni];
  }
  __syncthreads();

  float S[4];
#pragma unroll
  for (int ni = 0; ni < 4; ++ni) {
    const float* rp = &rs[ni * 16 + l15][0];
    f32x4 a = *(const f32x4*)(rp + 0);
    f32x4 b = *(const f32x4*)(rp + 4);
    f32x4 c = *(const f32x4*)(rp + 8);
    f32x4 d = *(const f32x4*)(rp + 12);
    S[ni] = ((a[0] + a[1] + a[2] + a[3]) + (b[0] + b[1] + b[2] + b[3])) +
            ((c[0] + c[1] + c[2] + c[3]) + (d[0] + d[1] + d[2] + d[3]));
  }

  // ---- dist stores (exposed tail) ----
#pragma unroll
  for (int ni = 0; ni < 4; ++ni) {
    size_t roff = (size_t)(ni * 16 + l15) * N_DIM;
#pragma unroll
    for (int mi = 0; mi < 4; ++mi) {
      f32x4 lv = acc[mi][ni];
      f32x4 d;
#pragma unroll
      for (int j = 0; j < 4; ++j)
        d[j] = sqrtf(fmaxf(S[ni] - 2.0f * ALPHA_F * lv[j] + a2, 0.0f));
      *(f32x4*)(Db + roff + mi * 16) = d;
    }
  }
}

extern "C" void kernel_launch(void* const* d_in, const int* in_sizes, int n_in,
                              void* d_out, int out_size, void* d_ws, size_t ws_size,
                              hipStream_t stream) {
  const float* x = (const float*)d_in[0];  // 16384 x 768
  const float* W = (const float*)d_in[1];  // 1024 x 768
  float* logits = (float*)d_out;
  float* dist = logits + (size_t)M_DIM * N_DIM;

  unsigned short* Wq = (unsigned short*)d_ws;  // 1.5 MB packed

  cvt_w_kernel<<<(N_DIM * K_DIM / 8) / 256, 256, 0, stream>>>(W, Wq);
  fused_kernel<<<M_DIM / 64, 1024, 0, stream>>>(x, Wq, logits, dist);
}